// Round 1
// baseline (1482.177 us; speedup 1.0000x reference)
//
#include <hip/hip_runtime.h>

#define I_DIM 32
#define J_DIM 32
#define S_DIM 256
#define H_DIM 768
#define ST 64   // s-tile rows per iteration
#define KC 32   // k-chunk (H) per staging step

// ---------------------------------------------------------------------------
// Kernel 1: inverse L2 norms for all Q rows (I*S) and K rows (J*S).
// One block per row; 256 threads, 3 elements each (H=768).
// ---------------------------------------------------------------------------
__global__ __launch_bounds__(256) void li_norm_kernel(
    const float* __restrict__ qe, const float* __restrict__ ke,
    float* __restrict__ qinv, float* __restrict__ kinv)
{
    const int row = blockIdx.x;
    const int tid = threadIdx.x;
    const float* base;
    float* dst;
    if (row < I_DIM * S_DIM) {
        base = qe + (size_t)row * H_DIM;
        dst  = qinv + row;
    } else {
        const int r = row - I_DIM * S_DIM;
        base = ke + (size_t)r * H_DIM;
        dst  = kinv + r;
    }
    float a = base[tid];
    float b = base[tid + 256];
    float c = base[tid + 512];
    float ss = a * a + b * b + c * c;
    #pragma unroll
    for (int m = 1; m < 64; m <<= 1) ss += __shfl_xor(ss, m, 64);
    __shared__ float red[4];
    if ((tid & 63) == 0) red[tid >> 6] = ss;
    __syncthreads();
    if (tid == 0) {
        float t = red[0] + red[1] + red[2] + red[3];
        *dst = 1.0f / fmaxf(sqrtf(t), 1e-12f);  // matches clip(norm, 1e-12)
    }
}

// ---------------------------------------------------------------------------
// Kernel 2: decay table dtab[d] = exp(-softplus(alpha_raw) * d), d in [0,256)
// ---------------------------------------------------------------------------
__global__ void li_dtab_kernel(const float* __restrict__ alpha_raw,
                               float* __restrict__ dtab)
{
    const float x = alpha_raw[0];
    const float alpha = (x > 20.0f) ? x : log1pf(expf(x));  // softplus
    const int t = threadIdx.x;
    dtab[t] = expf(-alpha * (float)t);
}

// ---------------------------------------------------------------------------
// Kernel 3: per (i,j) pair: C = Qn_i * Kn_j^T (256x256 over H=768), fused
// row-softmax over decayed/masked logits, score = sum_t p*c, then
// sum_s score*qmask / denom.  score identity: agg never materialized.
// ---------------------------------------------------------------------------
__global__ __launch_bounds__(256, 3) void li_score_kernel(
    const float* __restrict__ qe, const float* __restrict__ ke,
    const float* __restrict__ qm, const float* __restrict__ km,
    const float* __restrict__ qinv, const float* __restrict__ kinv,
    const float* __restrict__ dtab, float* __restrict__ out)
{
    // k-major LDS tiles, XOR-swizzled columns (write ≤2-way, read uniform)
    __shared__ __align__(16) float Qs[KC][ST];     // 8 KB
    __shared__ __align__(16) float Ks[KC][S_DIM];  // 32 KB
    __shared__ float dsh[S_DIM];
    __shared__ float kmsh[S_DIM];
    __shared__ float qmsh[S_DIM];
    __shared__ float kish[S_DIM];
    __shared__ float qish[S_DIM];
    __shared__ float redA[256];
    __shared__ float redB[256];

    const int tid = threadIdx.x;
    const int i = blockIdx.x >> 5;
    const int j = blockIdx.x & 31;
    const float* qbase = qe + (size_t)i * S_DIM * H_DIM;
    const float* kbase = ke + (size_t)j * S_DIM * H_DIM;

    dsh[tid]  = dtab[tid];
    kmsh[tid] = km[j * S_DIM + tid];
    qmsh[tid] = qm[i * S_DIM + tid];
    kish[tid] = kinv[j * S_DIM + tid];
    qish[tid] = qinv[i * S_DIM + tid];
    __syncthreads();

    const int tx  = tid & 31;   // t-column group: cols tx*8 .. tx*8+7
    const int ty  = tid >> 5;   // s-row group:   rows ty*8 .. ty*8+7
    const int kk4 = tid & 7;    // staging: which float4 along k
    const int slb = tid >> 3;   // staging: row within 32-row slab
    const int xw  = kk4 << 3;   // write-side XOR swizzle

    float total = 0.0f;

    for (int st = 0; st < S_DIM; st += ST) {
        float acc[8][8];
        #pragma unroll
        for (int r = 0; r < 8; ++r)
            #pragma unroll
            for (int c = 0; c < 8; ++c) acc[r][c] = 0.0f;

        for (int kb = 0; kb < H_DIM; kb += KC) {
            // ---- stage Q tile (64 s-rows x 32 k), normalized, k-major ----
            #pragma unroll
            for (int rr = 0; rr < 2; ++rr) {
                const int sl = slb + rr * 32;
                const float4 v = *(const float4*)(qbase + (size_t)(st + sl) * H_DIM + kb + kk4 * 4);
                const float inv = qish[st + sl];
                const int col = sl ^ xw;
                Qs[kk4 * 4 + 0][col] = v.x * inv;
                Qs[kk4 * 4 + 1][col] = v.y * inv;
                Qs[kk4 * 4 + 2][col] = v.z * inv;
                Qs[kk4 * 4 + 3][col] = v.w * inv;
            }
            // ---- stage K tile (256 t-rows x 32 k), normalized, k-major ----
            #pragma unroll
            for (int tt = 0; tt < 8; ++tt) {
                const int t = slb + tt * 32;
                const float4 v = *(const float4*)(kbase + (size_t)t * H_DIM + kb + kk4 * 4);
                const float inv = kish[t];
                const int col = t ^ xw;
                Ks[kk4 * 4 + 0][col] = v.x * inv;
                Ks[kk4 * 4 + 1][col] = v.y * inv;
                Ks[kk4 * 4 + 2][col] = v.z * inv;
                Ks[kk4 * 4 + 3][col] = v.w * inv;
            }
            __syncthreads();

            // ---- 8x8 micro-tile FMA over this k-chunk ----
            #pragma unroll 8
            for (int kk = 0; kk < KC; ++kk) {
                const int xr = ((kk >> 2) & 7) << 3;
                const int qcol = (ty * 8) ^ xr;
                const int kcol = (tx * 8) ^ xr;
                const float4 qa  = *(const float4*)&Qs[kk][qcol];
                const float4 qb  = *(const float4*)&Qs[kk][qcol + 4];
                const float4 ka  = *(const float4*)&Ks[kk][kcol];
                const float4 kb2 = *(const float4*)&Ks[kk][kcol + 4];
                const float qv[8] = {qa.x, qa.y, qa.z, qa.w, qb.x, qb.y, qb.z, qb.w};
                const float kv[8] = {ka.x, ka.y, ka.z, ka.w, kb2.x, kb2.y, kb2.z, kb2.w};
                #pragma unroll
                for (int r = 0; r < 8; ++r)
                    #pragma unroll
                    for (int c = 0; c < 8; ++c)
                        acc[r][c] = fmaf(qv[r], kv[c], acc[r][c]);
            }
            __syncthreads();
        }

        // ---- fused softmax + weighted-sum epilogue per s-row ----
        #pragma unroll
        for (int r = 0; r < 8; ++r) {
            const int s = st + ty * 8 + r;
            const float qms = qmsh[s];
            float mvals[8], cvals[8];
            float mloc = -3.0e38f;
            #pragma unroll
            for (int c = 0; c < 8; ++c) {
                const int t = tx * 8 + c;
                const float cv = acc[r][c];
                int dd = s - t; dd = dd < 0 ? -dd : dd;
                const float valid = qms * kmsh[t];
                const float m = cv * dsh[dd] * valid - (1.0f - valid) * 1e9f;
                mvals[c] = m;
                cvals[c] = cv;
                mloc = fmaxf(mloc, m);
            }
            #pragma unroll
            for (int mm = 1; mm < 32; mm <<= 1)
                mloc = fmaxf(mloc, __shfl_xor(mloc, mm, 32));
            float L = 0.0f, W = 0.0f;
            #pragma unroll
            for (int c = 0; c < 8; ++c) {
                const float e = expf(mvals[c] - mloc);
                L += e;
                W += e * cvals[c];
            }
            #pragma unroll
            for (int mm = 1; mm < 32; mm <<= 1) {
                L += __shfl_xor(L, mm, 32);
                W += __shfl_xor(W, mm, 32);
            }
            if (tx == 0) total += (W / L) * qms;
        }
    }

    // ---- block reduction: sum of row scores, and denom = clip(sum qmask,1) ----
    redA[tid] = total;
    redB[tid] = qmsh[tid];
    __syncthreads();
    for (int off = 128; off > 0; off >>= 1) {
        if (tid < off) {
            redA[tid] += redA[tid + off];
            redB[tid] += redB[tid + off];
        }
        __syncthreads();
    }
    if (tid == 0) out[blockIdx.x] = redA[0] / fmaxf(redB[0], 1.0f);
}

// ---------------------------------------------------------------------------
extern "C" void kernel_launch(void* const* d_in, const int* in_sizes, int n_in,
                              void* d_out, int out_size, void* d_ws, size_t ws_size,
                              hipStream_t stream)
{
    const float* qe = (const float*)d_in[0];   // [32,256,768]
    const float* ke = (const float*)d_in[1];   // [32,256,768]
    const float* qm = (const float*)d_in[2];   // [32,256]
    const float* km = (const float*)d_in[3];   // [32,256]
    const float* al = (const float*)d_in[4];   // scalar
    float* out = (float*)d_out;                // [32,32]

    float* qinv = (float*)d_ws;                 // 8192 floats
    float* kinv = qinv + I_DIM * S_DIM;         // 8192 floats
    float* dtab = kinv + J_DIM * S_DIM;         // 256 floats

    hipLaunchKernelGGL(li_norm_kernel, dim3(I_DIM * S_DIM + J_DIM * S_DIM), dim3(256),
                       0, stream, qe, ke, qinv, kinv);
    hipLaunchKernelGGL(li_dtab_kernel, dim3(1), dim3(256), 0, stream, al, dtab);
    hipLaunchKernelGGL(li_score_kernel, dim3(I_DIM * J_DIM), dim3(256), 0, stream,
                       qe, ke, qm, km, qinv, kinv, dtab, out);
}

// Round 2
// 1447.976 us; speedup vs baseline: 1.0236x; 1.0236x over previous
//
#include <hip/hip_runtime.h>

#define I_DIM 32
#define J_DIM 32
#define S_DIM 256
#define H_DIM 768
#define ST 64   // s-tile rows per iteration
#define KC 32   // k-chunk (H) per staging step

// ---------------------------------------------------------------------------
// Kernel 1: inverse L2 norms for all Q rows (I*S) and K rows (J*S).
// ---------------------------------------------------------------------------
__global__ __launch_bounds__(256) void li_norm_kernel(
    const float* __restrict__ qe, const float* __restrict__ ke,
    float* __restrict__ qinv, float* __restrict__ kinv)
{
    const int row = blockIdx.x;
    const int tid = threadIdx.x;
    const float* base;
    float* dst;
    if (row < I_DIM * S_DIM) {
        base = qe + (size_t)row * H_DIM;
        dst  = qinv + row;
    } else {
        const int r = row - I_DIM * S_DIM;
        base = ke + (size_t)r * H_DIM;
        dst  = kinv + r;
    }
    float a = base[tid];
    float b = base[tid + 256];
    float c = base[tid + 512];
    float ss = a * a + b * b + c * c;
    #pragma unroll
    for (int m = 1; m < 64; m <<= 1) ss += __shfl_xor(ss, m, 64);
    __shared__ float red[4];
    if ((tid & 63) == 0) red[tid >> 6] = ss;
    __syncthreads();
    if (tid == 0) {
        float t = red[0] + red[1] + red[2] + red[3];
        *dst = 1.0f / fmaxf(sqrtf(t), 1e-12f);
    }
}

// ---------------------------------------------------------------------------
// Kernel 2: decay table dtab[d] = exp(-softplus(alpha_raw) * d)
// ---------------------------------------------------------------------------
__global__ void li_dtab_kernel(const float* __restrict__ alpha_raw,
                               float* __restrict__ dtab)
{
    const float x = alpha_raw[0];
    const float alpha = (x > 20.0f) ? x : log1pf(expf(x));
    const int t = threadIdx.x;
    dtab[t] = expf(-alpha * (float)t);
}

// ---------------------------------------------------------------------------
// Kernel 3: per (i,j): C = Qn_i * Kn_j^T fused with row-softmax score.
// Micro-tile: thread (tx,ty) owns rows {4ty..+3, 32+4ty..+3} (within s-tile)
// and cols {4tx..+3, 128+4tx..+3}. Stride-4 halves -> conflict-free b128.
// ---------------------------------------------------------------------------
__global__ __launch_bounds__(256, 3) void li_score_kernel(
    const float* __restrict__ qe, const float* __restrict__ ke,
    const float* __restrict__ qm, const float* __restrict__ km,
    const float* __restrict__ qinv, const float* __restrict__ kinv,
    const float* __restrict__ dtab, float* __restrict__ out)
{
    __shared__ __align__(16) float Qs[KC][ST];     // 8 KB, k-major, XOR-swizzled
    __shared__ __align__(16) float Ks[KC][S_DIM];  // 32 KB
    __shared__ float dsh[S_DIM];
    __shared__ float kmsh[S_DIM];
    __shared__ float qmsh[S_DIM];
    __shared__ float kish[S_DIM];
    __shared__ float qish[S_DIM];
    __shared__ float redA[256];
    __shared__ float redB[256];

    const int tid = threadIdx.x;
    const int i = blockIdx.x >> 5;
    const int j = blockIdx.x & 31;
    const float* qbase = qe + (size_t)i * S_DIM * H_DIM;
    const float* kbase = ke + (size_t)j * S_DIM * H_DIM;

    dsh[tid]  = dtab[tid];
    kmsh[tid] = km[j * S_DIM + tid];
    qmsh[tid] = qm[i * S_DIM + tid];
    kish[tid] = kinv[j * S_DIM + tid];
    qish[tid] = qinv[i * S_DIM + tid];
    __syncthreads();

    const int tx  = tid & 31;
    const int ty  = tid >> 5;
    const int kk4 = tid & 7;    // staging: which float4 along k
    const int slb = tid >> 3;   // staging: row within 32-row slab
    const int xw  = kk4 << 3;   // write-side XOR swizzle (matches read xr)

    float total = 0.0f;

    for (int st = 0; st < S_DIM; st += ST) {
        float acc[8][8];
        #pragma unroll
        for (int r = 0; r < 8; ++r)
            #pragma unroll
            for (int c = 0; c < 8; ++c) acc[r][c] = 0.0f;

        for (int kb = 0; kb < H_DIM; kb += KC) {
            // ---- stage Q tile (64 s-rows x 32 k), normalized, k-major ----
            #pragma unroll
            for (int rr = 0; rr < 2; ++rr) {
                const int sl = slb + rr * 32;
                const float4 v = *(const float4*)(qbase + (size_t)(st + sl) * H_DIM + kb + kk4 * 4);
                const float inv = qish[st + sl];
                const int col = sl ^ xw;
                Qs[kk4 * 4 + 0][col] = v.x * inv;
                Qs[kk4 * 4 + 1][col] = v.y * inv;
                Qs[kk4 * 4 + 2][col] = v.z * inv;
                Qs[kk4 * 4 + 3][col] = v.w * inv;
            }
            // ---- stage K tile (256 t-rows x 32 k), normalized, k-major ----
            #pragma unroll
            for (int tt = 0; tt < 8; ++tt) {
                const int t = slb + tt * 32;
                const float4 v = *(const float4*)(kbase + (size_t)t * H_DIM + kb + kk4 * 4);
                const float inv = kish[t];
                const int col = t ^ xw;
                Ks[kk4 * 4 + 0][col] = v.x * inv;
                Ks[kk4 * 4 + 1][col] = v.y * inv;
                Ks[kk4 * 4 + 2][col] = v.z * inv;
                Ks[kk4 * 4 + 3][col] = v.w * inv;
            }
            __syncthreads();

            // ---- 8x8 micro-tile FMA over this k-chunk ----
            #pragma unroll 8
            for (int kk = 0; kk < KC; ++kk) {
                const int xr = ((kk >> 2) & 7) << 3;
                const float4 qa  = *(const float4*)&Qs[kk][(4 * ty) ^ xr];
                const float4 qb  = *(const float4*)&Qs[kk][(32 + 4 * ty) ^ xr];
                const float4 ka  = *(const float4*)&Ks[kk][(4 * tx) ^ xr];
                const float4 kb2 = *(const float4*)&Ks[kk][(128 + 4 * tx) ^ xr];
                const float qv[8] = {qa.x, qa.y, qa.z, qa.w, qb.x, qb.y, qb.z, qb.w};
                const float kv[8] = {ka.x, ka.y, ka.z, ka.w, kb2.x, kb2.y, kb2.z, kb2.w};
                #pragma unroll
                for (int r = 0; r < 8; ++r)
                    #pragma unroll
                    for (int c = 0; c < 8; ++c)
                        acc[r][c] = fmaf(qv[r], kv[c], acc[r][c]);
            }
            __syncthreads();
        }

        // ---- fused softmax + weighted-sum epilogue per owned s-row ----
        #pragma unroll
        for (int rh = 0; rh < 2; ++rh) {
            #pragma unroll
            for (int u = 0; u < 4; ++u) {
                const int s = st + rh * 32 + 4 * ty + u;
                const float qms = qmsh[s];
                float mvals[8], cvals[8];
                float mloc = -3.0e38f;
                #pragma unroll
                for (int ch = 0; ch < 2; ++ch) {
                    #pragma unroll
                    for (int v = 0; v < 4; ++v) {
                        const int t = ch * 128 + 4 * tx + v;
                        const float cv = acc[rh * 4 + u][ch * 4 + v];
                        int dd = s - t; dd = dd < 0 ? -dd : dd;
                        const float valid = qms * kmsh[t];
                        const float m = cv * dsh[dd] * valid - (1.0f - valid) * 1e9f;
                        mvals[ch * 4 + v] = m;
                        cvals[ch * 4 + v] = cv;
                        mloc = fmaxf(mloc, m);
                    }
                }
                #pragma unroll
                for (int mm = 1; mm < 32; mm <<= 1)
                    mloc = fmaxf(mloc, __shfl_xor(mloc, mm, 32));
                float L = 0.0f, W = 0.0f;
                #pragma unroll
                for (int c = 0; c < 8; ++c) {
                    const float e = __expf(mvals[c] - mloc);
                    L += e;
                    W += e * cvals[c];
                }
                #pragma unroll
                for (int mm = 1; mm < 32; mm <<= 1) {
                    L += __shfl_xor(L, mm, 32);
                    W += __shfl_xor(W, mm, 32);
                }
                if (tx == 0) total += (W / L) * qms;
            }
        }
    }

    // ---- block reduction: sum of row scores; denom = clip(sum qmask, 1) ----
    redA[tid] = total;
    redB[tid] = qmsh[tid];
    __syncthreads();
    for (int off = 128; off > 0; off >>= 1) {
        if (tid < off) {
            redA[tid] += redA[tid + off];
            redB[tid] += redB[tid + off];
        }
        __syncthreads();
    }
    if (tid == 0) out[blockIdx.x] = redA[0] / fmaxf(redB[0], 1.0f);
}

// ---------------------------------------------------------------------------
extern "C" void kernel_launch(void* const* d_in, const int* in_sizes, int n_in,
                              void* d_out, int out_size, void* d_ws, size_t ws_size,
                              hipStream_t stream)
{
    const float* qe = (const float*)d_in[0];   // [32,256,768]
    const float* ke = (const float*)d_in[1];   // [32,256,768]
    const float* qm = (const float*)d_in[2];   // [32,256]
    const float* km = (const float*)d_in[3];   // [32,256]
    const float* al = (const float*)d_in[4];   // scalar
    float* out = (float*)d_out;                // [32,32]

    float* qinv = (float*)d_ws;                 // 8192 floats
    float* kinv = qinv + I_DIM * S_DIM;         // 8192 floats
    float* dtab = kinv + J_DIM * S_DIM;         // 256 floats

    hipLaunchKernelGGL(li_norm_kernel, dim3(I_DIM * S_DIM + J_DIM * S_DIM), dim3(256),
                       0, stream, qe, ke, qinv, kinv);
    hipLaunchKernelGGL(li_dtab_kernel, dim3(1), dim3(256), 0, stream, al, dtab);
    hipLaunchKernelGGL(li_score_kernel, dim3(I_DIM * J_DIM), dim3(256), 0, stream,
                       qe, ke, qm, km, qinv, kinv, dtab, out);
}

// Round 3
// 422.841 us; speedup vs baseline: 3.5053x; 3.4244x over previous
//
#include <hip/hip_runtime.h>

#define I_DIM 32
#define J_DIM 32
#define S_DIM 256
#define H_DIM 768
#define KC    32                  // f16 elems per K-chunk
#define NCH   (H_DIM / KC)        // 24 chunks
#define QTILE_B 16384             // 128 rows x 128 B (h|l interleaved, swizzled)
#define KTILE_B 32768             // 256 rows x 128 B
#define WSQ_BYTES (I_DIM * 2 * NCH * QTILE_B)   // 25165824
#define WSK_BYTES (J_DIM * NCH * KTILE_B)       // 25165824
#define DTAB_OFF  (WSQ_BYTES + WSK_BYTES)       // 50331648

typedef _Float16 f16x8 __attribute__((ext_vector_type(8)));
typedef float    f32x16 __attribute__((ext_vector_type(16)));

static __device__ __forceinline__ unsigned short f16bits(_Float16 h) {
    union { _Float16 f; unsigned short u; } cv; cv.f = h; return cv.u;
}

// ---------------------------------------------------------------------------
// Pre-pass: normalize each row, split into fp16 hi + fp16 residual, and write
// to ws in the exact (pre-swizzled) LDS tile image.
// Tile image: row rr occupies 128 B: slot(4b k-group | isLo<<2) ^ (rr&7), 16B slots.
// grid = (I+J)*S blocks x 192 threads (4 k-elems each).
// ---------------------------------------------------------------------------
__global__ __launch_bounds__(192) void li_split_kernel(
    const float* __restrict__ qe, const float* __restrict__ ke,
    char* __restrict__ wsQ, char* __restrict__ wsK)
{
    const int b = blockIdx.x;
    const int t = threadIdx.x;
    const bool isQ = b < I_DIM * S_DIM;
    const int row = isQ ? b : b - I_DIM * S_DIM;
    const float* base = (isQ ? qe : ke) + (size_t)row * H_DIM;

    const float4 v = *(const float4*)(base + 4 * t);
    float ss = v.x * v.x + v.y * v.y + v.z * v.z + v.w * v.w;
    #pragma unroll
    for (int m = 1; m < 64; m <<= 1) ss += __shfl_xor(ss, m, 64);
    __shared__ float red3[3];
    if ((t & 63) == 0) red3[t >> 6] = ss;
    __syncthreads();
    const float inv = 1.0f / fmaxf(sqrtf(red3[0] + red3[1] + red3[2]), 1e-12f);

    float xn[4] = {v.x * inv, v.y * inv, v.z * inv, v.w * inv};
    unsigned short hb[4], lb[4];
    #pragma unroll
    for (int e = 0; e < 4; ++e) {
        _Float16 h = (_Float16)xn[e];
        _Float16 lo = (_Float16)(xn[e] - (float)h);
        hb[e] = f16bits(h);
        lb[e] = f16bits(lo);
    }
    const unsigned int h01 = hb[0] | ((unsigned int)hb[1] << 16);
    const unsigned int h23 = hb[2] | ((unsigned int)hb[3] << 16);
    const unsigned int l01 = lb[0] | ((unsigned int)lb[1] << 16);
    const unsigned int l23 = lb[2] | ((unsigned int)lb[3] << 16);

    const int mi = row >> 8;        // i or j
    const int s  = row & 255;
    const int k0 = 4 * t;
    const int c  = k0 >> 5;         // chunk
    const int kk = k0 & 31;         // k within chunk

    char* tile; int rr;
    if (isQ) { tile = wsQ + (size_t)((mi * 2 + (s >> 7)) * NCH + c) * QTILE_B; rr = s & 127; }
    else     { tile = wsK + (size_t)(mi * NCH + c) * KTILE_B;                  rr = s; }

    const int sh  = ((kk >> 3) ^ (rr & 7)) << 4;
    const int sl  = (((kk >> 3) | 4) ^ (rr & 7)) << 4;
    const int off = (kk & 7) * 2;   // 0 or 8
    *(uint2*)(tile + rr * 128 + sh + off) = make_uint2(h01, h23);
    *(uint2*)(tile + rr * 128 + sl + off) = make_uint2(l01, l23);
}

// ---------------------------------------------------------------------------
// dtab[d] = exp(-softplus(alpha_raw) * d)
// ---------------------------------------------------------------------------
__global__ void li_dtab_kernel(const float* __restrict__ alpha_raw,
                               float* __restrict__ dtab)
{
    const float x = alpha_raw[0];
    const float alpha = (x > 20.0f) ? x : log1pf(expf(x));
    dtab[threadIdx.x] = expf(-alpha * (float)threadIdx.x);
}

// ---------------------------------------------------------------------------
// Main: per (i,j) block; 2 s-tiles of 128 rows; wave wid owns rows
// [32*wid, 32*wid+32) x all 256 cols as 8 MFMA 32x32 tiles.
// 3-term split GEMM: qh*kh + qh*kl + ql*kh. Fused row-softmax score.
// ---------------------------------------------------------------------------
__global__ __launch_bounds__(256, 2) void li_mfma_kernel(
    const char* __restrict__ wsQ, const char* __restrict__ wsK,
    const float* __restrict__ qm, const float* __restrict__ km,
    const float* __restrict__ dtab, float* __restrict__ out)
{
    __shared__ __align__(16) char sQ[QTILE_B];
    __shared__ __align__(16) char sK[KTILE_B];
    __shared__ float dsh[256], kmsh[256], qmsh[256], redA[256], redB[256];

    const int tid = threadIdx.x;
    const int wid = tid >> 6;
    const int l   = tid & 63;
    const int l31 = l & 31;
    const int hi  = l >> 5;

    // XCD-aware mapping: XCD x = bid%8 hosts j in {4x..4x+3} -> K_j L2-resident
    const int bidx = blockIdx.x;
    const int x  = bidx & 7;
    const int r0 = bidx >> 3;
    const int j  = x * 4 + (r0 & 3);
    const int i  = r0 >> 2;

    dsh[tid]  = dtab[tid];
    kmsh[tid] = km[j * 256 + tid];
    qmsh[tid] = qm[i * 256 + tid];
    __syncthreads();

    float total = 0.0f;

    for (int st = 0; st < 2; ++st) {
        f32x16 acc[8];
        #pragma unroll
        for (int nt = 0; nt < 8; ++nt)
            #pragma unroll
            for (int z = 0; z < 16; ++z) acc[nt][z] = 0.0f;

        for (int c = 0; c < NCH; ++c) {
            const char* qt = wsQ + (size_t)((i * 2 + st) * NCH + c) * QTILE_B;
            const char* kt = wsK + (size_t)(j * NCH + c) * KTILE_B;
            // stage 48 KB via global_load_lds (ws image == LDS image, identity copy)
            #pragma unroll
            for (int u = 0; u < 4; ++u)
                __builtin_amdgcn_global_load_lds(
                    (const __attribute__((address_space(1))) void*)(qt + wid * 4096 + u * 1024 + l * 16),
                    (__attribute__((address_space(3))) void*)(sQ + wid * 4096 + u * 1024), 16, 0, 0);
            #pragma unroll
            for (int u = 0; u < 8; ++u)
                __builtin_amdgcn_global_load_lds(
                    (const __attribute__((address_space(1))) void*)(kt + wid * 8192 + u * 1024 + l * 16),
                    (__attribute__((address_space(3))) void*)(sK + wid * 8192 + u * 1024), 16, 0, 0);
            __syncthreads();

            #pragma unroll
            for (int ks = 0; ks < 2; ++ks) {
                const int kkb = ks * 16 + hi * 8;
                const int r7  = l31 & 7;
                const int sH  = (((kkb >> 3)) ^ r7) << 4;
                const int sL  = (((kkb >> 3) | 4) ^ r7) << 4;
                const int rq  = wid * 32 + l31;
                const f16x8 qh = *(const f16x8*)(sQ + rq * 128 + sH);
                const f16x8 ql = *(const f16x8*)(sQ + rq * 128 + sL);
                #pragma unroll
                for (int nt = 0; nt < 8; ++nt) {
                    const int rk = nt * 32 + l31;
                    const f16x8 kh = *(const f16x8*)(sK + rk * 128 + sH);
                    const f16x8 kl = *(const f16x8*)(sK + rk * 128 + sL);
                    acc[nt] = __builtin_amdgcn_mfma_f32_32x32x16_f16(qh, kh, acc[nt], 0, 0, 0);
                    acc[nt] = __builtin_amdgcn_mfma_f32_32x32x16_f16(qh, kl, acc[nt], 0, 0, 0);
                    acc[nt] = __builtin_amdgcn_mfma_f32_32x32x16_f16(ql, kh, acc[nt], 0, 0, 0);
                }
            }
            __syncthreads();
        }

        // fused softmax + weighted-sum; each row lives entirely in one wave
        #pragma unroll
        for (int reg = 0; reg < 16; ++reg) {
            const int srow = st * 128 + wid * 32 + hi * 4 + (reg & 3) + 8 * (reg >> 2);
            const float qms = qmsh[srow];
            float mv[8], cvv[8];
            float mloc = -3.0e38f;
            #pragma unroll
            for (int nt = 0; nt < 8; ++nt) {
                const int tcol = nt * 32 + l31;
                const float cv = acc[nt][reg];
                int dd = srow - tcol; dd = dd < 0 ? -dd : dd;
                const float valid = qms * kmsh[tcol];
                const float m = cv * dsh[dd] * valid - (1.0f - valid) * 1e9f;
                mv[nt] = m; cvv[nt] = cv;
                mloc = fmaxf(mloc, m);
            }
            #pragma unroll
            for (int mm = 1; mm < 32; mm <<= 1)
                mloc = fmaxf(mloc, __shfl_xor(mloc, mm, 32));
            float L = 0.0f, W = 0.0f;
            #pragma unroll
            for (int nt = 0; nt < 8; ++nt) {
                const float e = __expf(mv[nt] - mloc);
                L += e;
                W += e * cvv[nt];
            }
            #pragma unroll
            for (int mm = 1; mm < 32; mm <<= 1) {
                L += __shfl_xor(L, mm, 32);
                W += __shfl_xor(W, mm, 32);
            }
            if (l31 == 0) total += (W / L) * qms;
        }
    }

    redA[tid] = total;
    redB[tid] = qmsh[tid];
    __syncthreads();
    for (int off = 128; off > 0; off >>= 1) {
        if (tid < off) {
            redA[tid] += redA[tid + off];
            redB[tid] += redB[tid + off];
        }
        __syncthreads();
    }
    if (tid == 0) out[i * 32 + j] = redA[0] / fmaxf(redB[0], 1.0f);
}

// ---------------------------------------------------------------------------
extern "C" void kernel_launch(void* const* d_in, const int* in_sizes, int n_in,
                              void* d_out, int out_size, void* d_ws, size_t ws_size,
                              hipStream_t stream)
{
    const float* qe = (const float*)d_in[0];
    const float* ke = (const float*)d_in[1];
    const float* qm = (const float*)d_in[2];
    const float* km = (const float*)d_in[3];
    const float* al = (const float*)d_in[4];
    float* out = (float*)d_out;

    char* ws   = (char*)d_ws;
    char* wsQ  = ws;
    char* wsK  = ws + WSQ_BYTES;
    float* dtab = (float*)(ws + DTAB_OFF);

    hipLaunchKernelGGL(li_split_kernel, dim3((I_DIM + J_DIM) * S_DIM), dim3(192),
                       0, stream, qe, ke, wsQ, wsK);
    hipLaunchKernelGGL(li_dtab_kernel, dim3(1), dim3(256), 0, stream, al, dtab);
    hipLaunchKernelGGL(li_mfma_kernel, dim3(I_DIM * J_DIM), dim3(256), 0, stream,
                       wsQ, wsK, qm, km, dtab, out);
}

// Round 5
// 416.280 us; speedup vs baseline: 3.5605x; 1.0158x over previous
//
#include <hip/hip_runtime.h>

#define I_DIM 32
#define J_DIM 32
#define S_DIM 256
#define H_DIM 768
#define KC    32                  // f16 elems per K-chunk
#define NCH   (H_DIM / KC)        // 24 chunks
#define TILE_B 32768              // 256 rows x 128 B (h|l slots, XOR-swizzled)
#define WSQ_BYTES ((size_t)I_DIM * NCH * TILE_B)   // 24 MB
#define WSK_BYTES ((size_t)J_DIM * NCH * TILE_B)   // 24 MB

typedef _Float16 f16x8 __attribute__((ext_vector_type(8)));
typedef float    f32x16 __attribute__((ext_vector_type(16)));

static __device__ __forceinline__ unsigned short f16bits(_Float16 h) {
    union { _Float16 f; unsigned short u; } cv; cv.f = h; return cv.u;
}

// ---------------------------------------------------------------------------
// Pre-pass: one wave per row. Normalize, split fp16 hi + fp16 residual, store
// in pre-swizzled LDS tile image: row s occupies 128 B; 16B slot for k-group
// kg (hi: kg, lo: kg^4 -> addr^64), slot index XOR (s&7).
// ---------------------------------------------------------------------------
__global__ __launch_bounds__(256) void li_split_kernel(
    const float* __restrict__ qe, const float* __restrict__ ke,
    char* __restrict__ wsQ, char* __restrict__ wsK)
{
    const int lane = threadIdx.x & 63;
    const int w    = threadIdx.x >> 6;
    const int r    = blockIdx.x * 4 + w;               // 0..16383
    const bool isQ = r < I_DIM * S_DIM;
    const int row  = isQ ? r : r - I_DIM * S_DIM;
    const float* base = (isQ ? qe : ke) + (size_t)row * H_DIM;

    float4 v[3];
    v[0] = *(const float4*)(base + 4 * lane);
    v[1] = *(const float4*)(base + 4 * lane + 256);
    v[2] = *(const float4*)(base + 4 * lane + 512);
    float ss = 0.0f;
    #pragma unroll
    for (int g = 0; g < 3; ++g)
        ss += v[g].x * v[g].x + v[g].y * v[g].y + v[g].z * v[g].z + v[g].w * v[g].w;
    #pragma unroll
    for (int m = 1; m < 64; m <<= 1) ss += __shfl_xor(ss, m, 64);
    const float inv = 1.0f / fmaxf(sqrtf(ss), 1e-12f);

    const int mi  = row >> 8;
    const int s   = row & 255;
    const int r7  = s & 7;
    char* wsb = (isQ ? wsQ : wsK) + (size_t)mi * NCH * TILE_B + s * 128;

    #pragma unroll
    for (int g = 0; g < 3; ++g) {
        const int k0 = 4 * lane + 256 * g;
        const int c  = k0 >> 5;
        const int kk = k0 & 31;
        float xn[4] = {v[g].x * inv, v[g].y * inv, v[g].z * inv, v[g].w * inv};
        unsigned short hb[4], lb[4];
        #pragma unroll
        for (int e = 0; e < 4; ++e) {
            _Float16 h  = (_Float16)xn[e];
            _Float16 lo = (_Float16)(xn[e] - (float)h);
            hb[e] = f16bits(h);
            lb[e] = f16bits(lo);
        }
        char* p = wsb + (size_t)c * TILE_B + (((kk >> 3) ^ r7) << 4) + (kk & 7) * 2;
        *(uint2*)(p)        = make_uint2(hb[0] | ((unsigned)hb[1] << 16), hb[2] | ((unsigned)hb[3] << 16));
        *(uint2*)((char*)((size_t)p ^ 64)) = make_uint2(lb[0] | ((unsigned)lb[1] << 16), lb[2] | ((unsigned)lb[3] << 16));
    }
}

// ---------------------------------------------------------------------------
// Main: 512 threads = 8 waves in a 4(row)x2(col) grid. Wave owns 64 rows x
// 128 cols = 2x4 MFMA 32x32 tiles. Double-buffered chunk staging:
// STAGE(c+1) -> compute(c) -> syncthreads (drain). Softmax col-halves merged
// via per-row (m,L,W) partials in LDS.
// ---------------------------------------------------------------------------
__global__ __launch_bounds__(512, 2) void li_mfma_kernel(
    const char* __restrict__ wsQ, const char* __restrict__ wsK,
    const float* __restrict__ qm, const float* __restrict__ km,
    const float* __restrict__ alpha_raw, float* __restrict__ out)
{
    __shared__ __align__(16) char sQ[2][TILE_B];
    __shared__ __align__(16) char sK[2][TILE_B];
    __shared__ float kmsh[256], qmsh[256];
    __shared__ float pm[256][2], pL[256][2], pW[256][2];
    __shared__ float redA[512], redB[512];

    const int tid = threadIdx.x;
    const int wid = tid >> 6;
    const int l   = tid & 63;
    const int l31 = l & 31;
    const int hi  = l >> 5;
    const int wx  = wid & 1;
    const int wy  = wid >> 1;
    const int r7  = l31 & 7;

    // XCD-aware: XCD x hosts j in {4x..4x+3} -> K_j stays L2-resident
    const int bidx = blockIdx.x;
    const int x  = bidx & 7;
    const int r0 = bidx >> 3;
    const int j  = x * 4 + (r0 & 3);
    const int i  = r0 >> 2;

    if (tid < 256) {
        kmsh[tid] = km[j * 256 + tid];
        qmsh[tid] = qm[i * 256 + tid];
    }
    const float araw  = alpha_raw[0];
    const float alpha = (araw > 20.0f) ? araw : log1pf(expf(araw));
    const float nal   = -alpha;

    const char* qbase = wsQ + (size_t)i * NCH * TILE_B;
    const char* kbase = wsK + (size_t)j * NCH * TILE_B;

    f32x16 acc[2][4];
    #pragma unroll
    for (int mr = 0; mr < 2; ++mr)
        #pragma unroll
        for (int nt = 0; nt < 4; ++nt)
            #pragma unroll
            for (int z = 0; z < 16; ++z) acc[mr][nt][z] = 0.0f;

#define STAGE(buf, c)                                                                      \
    do {                                                                                   \
        const char* qt_ = qbase + (size_t)(c) * TILE_B + wid * 4096 + l * 16;              \
        const char* kt_ = kbase + (size_t)(c) * TILE_B + wid * 4096 + l * 16;              \
        char* dq_ = sQ[buf] + wid * 4096;                                                  \
        char* dk_ = sK[buf] + wid * 4096;                                                  \
        _Pragma("unroll")                                                                  \
        for (int u = 0; u < 4; ++u)                                                        \
            __builtin_amdgcn_global_load_lds(                                              \
                (const __attribute__((address_space(1))) void*)(qt_ + u * 1024),           \
                (__attribute__((address_space(3))) void*)(dq_ + u * 1024), 16, 0, 0);      \
        _Pragma("unroll")                                                                  \
        for (int u = 0; u < 4; ++u)                                                        \
            __builtin_amdgcn_global_load_lds(                                              \
                (const __attribute__((address_space(1))) void*)(kt_ + u * 1024),           \
                (__attribute__((address_space(3))) void*)(dk_ + u * 1024), 16, 0, 0);      \
    } while (0)

    STAGE(0, 0);
    __syncthreads();

    for (int c = 0; c < NCH; ++c) {
        if (c + 1 < NCH) STAGE((c + 1) & 1, c + 1);
        const char* bQ = sQ[c & 1];
        const char* bK = sK[c & 1];
        #pragma unroll
        for (int ks = 0; ks < 2; ++ks) {
            const int soff = ((ks * 2 + hi) ^ r7) << 4;   // hi-slot byte offset
            const int rA = wy * 64 + l31;
            const int rB = rA + 32;
            const f16x8 qhA = *(const f16x8*)(bQ + rA * 128 + soff);
            const f16x8 qlA = *(const f16x8*)(bQ + ((rA * 128 + soff) ^ 64));
            const f16x8 qhB = *(const f16x8*)(bQ + rB * 128 + soff);
            const f16x8 qlB = *(const f16x8*)(bQ + ((rB * 128 + soff) ^ 64));
            f16x8 kh[4], kl[4];
            #pragma unroll
            for (int nt = 0; nt < 4; ++nt) {
                const int rk = wx * 128 + nt * 32 + l31;
                kh[nt] = *(const f16x8*)(bK + rk * 128 + soff);
                kl[nt] = *(const f16x8*)(bK + ((rk * 128 + soff) ^ 64));
            }
            #pragma unroll
            for (int nt = 0; nt < 4; ++nt) {
                acc[0][nt] = __builtin_amdgcn_mfma_f32_32x32x16_f16(qhA, kh[nt], acc[0][nt], 0, 0, 0);
                acc[1][nt] = __builtin_amdgcn_mfma_f32_32x32x16_f16(qhB, kh[nt], acc[1][nt], 0, 0, 0);
            }
            #pragma unroll
            for (int nt = 0; nt < 4; ++nt) {
                acc[0][nt] = __builtin_amdgcn_mfma_f32_32x32x16_f16(qhA, kl[nt], acc[0][nt], 0, 0, 0);
                acc[1][nt] = __builtin_amdgcn_mfma_f32_32x32x16_f16(qhB, kl[nt], acc[1][nt], 0, 0, 0);
            }
            #pragma unroll
            for (int nt = 0; nt < 4; ++nt) {
                acc[0][nt] = __builtin_amdgcn_mfma_f32_32x32x16_f16(qlA, kh[nt], acc[0][nt], 0, 0, 0);
                acc[1][nt] = __builtin_amdgcn_mfma_f32_32x32x16_f16(qlB, kh[nt], acc[1][nt], 0, 0, 0);
            }
        }
        __syncthreads();
    }
#undef STAGE

    // ---- per-wave softmax partials over its 128-col half ----
    #pragma unroll
    for (int mrep = 0; mrep < 2; ++mrep) {
        #pragma unroll
        for (int reg = 0; reg < 16; ++reg) {
            const int srow = wy * 64 + mrep * 32 + hi * 4 + (reg & 3) + 8 * (reg >> 2);
            const float qms = qmsh[srow];
            float mv[4], cvv[4];
            float mloc = -3.0e38f;
            #pragma unroll
            for (int nt = 0; nt < 4; ++nt) {
                const int tcol = wx * 128 + nt * 32 + l31;
                const float cv = acc[mrep][nt][reg];
                int dd = srow - tcol; dd = dd < 0 ? -dd : dd;
                const float valid = qms * kmsh[tcol];
                const float m = cv * __expf(nal * (float)dd) * valid - (1.0f - valid) * 1e9f;
                mv[nt] = m; cvv[nt] = cv;
                mloc = fmaxf(mloc, m);
            }
            #pragma unroll
            for (int mm = 1; mm < 32; mm <<= 1)
                mloc = fmaxf(mloc, __shfl_xor(mloc, mm, 32));
            float L = 0.0f, W = 0.0f;
            #pragma unroll
            for (int nt = 0; nt < 4; ++nt) {
                const float e = __expf(mv[nt] - mloc);
                L += e;
                W += e * cvv[nt];
            }
            #pragma unroll
            for (int mm = 1; mm < 32; mm <<= 1) {
                L += __shfl_xor(L, mm, 32);
                W += __shfl_xor(W, mm, 32);
            }
            if (l31 == 0) {
                pm[srow][wx] = mloc;
                pL[srow][wx] = L;
                pW[srow][wx] = W;
            }
        }
    }
    __syncthreads();

    // ---- merge col-halves per row, then block-reduce ----
    float contrib = 0.0f, qq = 0.0f;
    if (tid < 256) {
        const float m0 = pm[tid][0], m1 = pm[tid][1];
        const float M  = fmaxf(m0, m1);
        const float e0 = __expf(m0 - M), e1 = __expf(m1 - M);
        const float L  = pL[tid][0] * e0 + pL[tid][1] * e1;
        const float W  = pW[tid][0] * e0 + pW[tid][1] * e1;
        contrib = (W / L) * qmsh[tid];
        qq = qmsh[tid];
    }
    redA[tid] = contrib;
    redB[tid] = qq;
    __syncthreads();
    for (int off = 256; off > 0; off >>= 1) {
        if (tid < off) {
            redA[tid] += redA[tid + off];
            redB[tid] += redB[tid + off];
        }
        __syncthreads();
    }
    if (tid == 0) out[i * 32 + j] = redA[0] / fmaxf(redB[0], 1.0f);
}

// ---------------------------------------------------------------------------
extern "C" void kernel_launch(void* const* d_in, const int* in_sizes, int n_in,
                              void* d_out, int out_size, void* d_ws, size_t ws_size,
                              hipStream_t stream)
{
    const float* qe = (const float*)d_in[0];
    const float* ke = (const float*)d_in[1];
    const float* qm = (const float*)d_in[2];
    const float* km = (const float*)d_in[3];
    const float* al = (const float*)d_in[4];
    float* out = (float*)d_out;

    char* wsQ = (char*)d_ws;
    char* wsK = wsQ + WSQ_BYTES;

    hipLaunchKernelGGL(li_split_kernel, dim3((I_DIM + J_DIM) * S_DIM / 4), dim3(256),
                       0, stream, qe, ke, wsQ, wsK);
    hipLaunchKernelGGL(li_mfma_kernel, dim3(I_DIM * J_DIM), dim3(512), 0, stream,
                       wsQ, wsK, qm, km, al, out);
}

// Round 6
// 406.649 us; speedup vs baseline: 3.6449x; 1.0237x over previous
//
#include <hip/hip_runtime.h>

#define I_DIM 32
#define J_DIM 32
#define S_DIM 256
#define H_DIM 768
#define KC    32                  // f16 elems per K-chunk
#define NCH   (H_DIM / KC)        // 24 chunks
#define TILE_B 32768              // 256 rows x 128 B (h|l slots, XOR-swizzled)
#define WSQ_BYTES ((size_t)I_DIM * NCH * TILE_B)   // 24 MB
#define WSK_BYTES ((size_t)J_DIM * NCH * TILE_B)   // 24 MB

typedef _Float16 f16x8 __attribute__((ext_vector_type(8)));
typedef float    f32x16 __attribute__((ext_vector_type(16)));

static __device__ __forceinline__ unsigned short f16bits(_Float16 h) {
    union { _Float16 f; unsigned short u; } cv; cv.f = h; return cv.u;
}

// ---------------------------------------------------------------------------
// Pre-pass: one wave per row. Normalize, split fp16 hi + fp16 residual, store
// in pre-swizzled LDS tile image: row s occupies 128 B; 16B slot for k-group
// kg (hi: kg, lo: kg^4 -> addr^64), slot index XOR (s&7).
// ---------------------------------------------------------------------------
__global__ __launch_bounds__(256) void li_split_kernel(
    const float* __restrict__ qe, const float* __restrict__ ke,
    char* __restrict__ wsQ, char* __restrict__ wsK)
{
    const int lane = threadIdx.x & 63;
    const int w    = threadIdx.x >> 6;
    const int r    = blockIdx.x * 4 + w;               // 0..16383
    const bool isQ = r < I_DIM * S_DIM;
    const int row  = isQ ? r : r - I_DIM * S_DIM;
    const float* base = (isQ ? qe : ke) + (size_t)row * H_DIM;

    float4 v[3];
    v[0] = *(const float4*)(base + 4 * lane);
    v[1] = *(const float4*)(base + 4 * lane + 256);
    v[2] = *(const float4*)(base + 4 * lane + 512);
    float ss = 0.0f;
    #pragma unroll
    for (int g = 0; g < 3; ++g)
        ss += v[g].x * v[g].x + v[g].y * v[g].y + v[g].z * v[g].z + v[g].w * v[g].w;
    #pragma unroll
    for (int m = 1; m < 64; m <<= 1) ss += __shfl_xor(ss, m, 64);
    const float inv = 1.0f / fmaxf(sqrtf(ss), 1e-12f);

    const int mi  = row >> 8;
    const int s   = row & 255;
    const int r7  = s & 7;
    char* wsb = (isQ ? wsQ : wsK) + (size_t)mi * NCH * TILE_B + s * 128;

    #pragma unroll
    for (int g = 0; g < 3; ++g) {
        const int k0 = 4 * lane + 256 * g;
        const int c  = k0 >> 5;
        const int kk = k0 & 31;
        float xn[4] = {v[g].x * inv, v[g].y * inv, v[g].z * inv, v[g].w * inv};
        unsigned short hb[4], lb[4];
        #pragma unroll
        for (int e = 0; e < 4; ++e) {
            _Float16 h  = (_Float16)xn[e];
            _Float16 lo = (_Float16)(xn[e] - (float)h);
            hb[e] = f16bits(h);
            lb[e] = f16bits(lo);
        }
        char* p = wsb + (size_t)c * TILE_B + (((kk >> 3) ^ r7) << 4) + (kk & 7) * 2;
        *(uint2*)(p)        = make_uint2(hb[0] | ((unsigned)hb[1] << 16), hb[2] | ((unsigned)hb[3] << 16));
        *(uint2*)((char*)((size_t)p ^ 64)) = make_uint2(lb[0] | ((unsigned)lb[1] << 16), lb[2] | ((unsigned)lb[3] << 16));
    }
}

// ---------------------------------------------------------------------------
// Main: 512 threads = 8 waves in a 4(row)x2(col) grid. Wave owns 64 rows x
// 128 cols = 2x4 MFMA 32x32 tiles. Double-buffered chunk staging with
// COUNTED vmcnt (T3/T4): STAGE(c+1) -> vmcnt(8) -> s_barrier -> compute(c)
// -> s_barrier. Prefetch loads stay in flight across the barrier.
// ---------------------------------------------------------------------------
__global__ __launch_bounds__(512, 2) void li_mfma_kernel(
    const char* __restrict__ wsQ, const char* __restrict__ wsK,
    const float* __restrict__ qm, const float* __restrict__ km,
    const float* __restrict__ alpha_raw, float* __restrict__ out)
{
    __shared__ __align__(16) char sQ[2][TILE_B];
    __shared__ __align__(16) char sK[2][TILE_B];
    __shared__ float kmsh[256], qmsh[256];
    __shared__ float pm[256][2], pL[256][2], pW[256][2];
    __shared__ float redA[512], redB[512];

    const int tid = threadIdx.x;
    const int wid = tid >> 6;
    const int l   = tid & 63;
    const int l31 = l & 31;
    const int hi  = l >> 5;
    const int wx  = wid & 1;
    const int wy  = wid >> 1;
    const int r7  = l31 & 7;

    // XCD-aware: XCD x hosts j in {4x..4x+3} -> K_j stays L2-resident
    const int bidx = blockIdx.x;
    const int x  = bidx & 7;
    const int r0 = bidx >> 3;
    const int j  = x * 4 + (r0 & 3);
    const int i  = r0 >> 2;

    if (tid < 256) {
        kmsh[tid] = km[j * 256 + tid];
        qmsh[tid] = qm[i * 256 + tid];
    }
    const float araw  = alpha_raw[0];
    const float alpha = (araw > 20.0f) ? araw : log1pf(expf(araw));
    const float nal   = -alpha;

    const char* qbase = wsQ + (size_t)i * NCH * TILE_B;
    const char* kbase = wsK + (size_t)j * NCH * TILE_B;

    f32x16 acc[2][4];
    #pragma unroll
    for (int mr = 0; mr < 2; ++mr)
        #pragma unroll
        for (int nt = 0; nt < 4; ++nt)
            #pragma unroll
            for (int z = 0; z < 16; ++z) acc[mr][nt][z] = 0.0f;

#define STAGE(buf, c)                                                                      \
    do {                                                                                   \
        const char* qt_ = qbase + (size_t)(c) * TILE_B + wid * 4096 + l * 16;              \
        const char* kt_ = kbase + (size_t)(c) * TILE_B + wid * 4096 + l * 16;              \
        char* dq_ = sQ[buf] + wid * 4096;                                                  \
        char* dk_ = sK[buf] + wid * 4096;                                                  \
        _Pragma("unroll")                                                                  \
        for (int u = 0; u < 4; ++u)                                                        \
            __builtin_amdgcn_global_load_lds(                                              \
                (const __attribute__((address_space(1))) void*)(qt_ + u * 1024),           \
                (__attribute__((address_space(3))) void*)(dq_ + u * 1024), 16, 0, 0);      \
        _Pragma("unroll")                                                                  \
        for (int u = 0; u < 4; ++u)                                                        \
            __builtin_amdgcn_global_load_lds(                                              \
                (const __attribute__((address_space(1))) void*)(kt_ + u * 1024),           \
                (__attribute__((address_space(3))) void*)(dk_ + u * 1024), 16, 0, 0);      \
    } while (0)

    STAGE(0, 0);
    // Drain everything once (stage(0) + qm/km loads), then sync.
    asm volatile("s_waitcnt vmcnt(0)" ::: "memory");
    __builtin_amdgcn_sched_barrier(0);
    __builtin_amdgcn_s_barrier();
    __builtin_amdgcn_sched_barrier(0);

    for (int c = 0; c < NCH; ++c) {
        if (c + 1 < NCH) {
            STAGE((c + 1) & 1, c + 1);
            // Wait for chunk c's 8 loads (ours); chunk c+1's 8 stay in flight.
            asm volatile("s_waitcnt vmcnt(8)" ::: "memory");
        } else {
            asm volatile("s_waitcnt vmcnt(0)" ::: "memory");
        }
        __builtin_amdgcn_sched_barrier(0);
        __builtin_amdgcn_s_barrier();   // all waves' chunk-c LDS writes visible
        __builtin_amdgcn_sched_barrier(0);

        const char* bQ = sQ[c & 1];
        const char* bK = sK[c & 1];
        #pragma unroll
        for (int ks = 0; ks < 2; ++ks) {
            const int soff = ((ks * 2 + hi) ^ r7) << 4;   // hi-slot byte offset
            const int rA = wy * 64 + l31;
            const int rB = rA + 32;
            const f16x8 qhA = *(const f16x8*)(bQ + rA * 128 + soff);
            const f16x8 qlA = *(const f16x8*)(bQ + ((rA * 128 + soff) ^ 64));
            const f16x8 qhB = *(const f16x8*)(bQ + rB * 128 + soff);
            const f16x8 qlB = *(const f16x8*)(bQ + ((rB * 128 + soff) ^ 64));
            f16x8 kh[4], kl[4];
            #pragma unroll
            for (int nt = 0; nt < 4; ++nt) {
                const int rk = wx * 128 + nt * 32 + l31;
                kh[nt] = *(const f16x8*)(bK + rk * 128 + soff);
                kl[nt] = *(const f16x8*)(bK + ((rk * 128 + soff) ^ 64));
            }
            #pragma unroll
            for (int nt = 0; nt < 4; ++nt) {
                acc[0][nt] = __builtin_amdgcn_mfma_f32_32x32x16_f16(qhA, kh[nt], acc[0][nt], 0, 0, 0);
                acc[1][nt] = __builtin_amdgcn_mfma_f32_32x32x16_f16(qhB, kh[nt], acc[1][nt], 0, 0, 0);
            }
            #pragma unroll
            for (int nt = 0; nt < 4; ++nt) {
                acc[0][nt] = __builtin_amdgcn_mfma_f32_32x32x16_f16(qhA, kl[nt], acc[0][nt], 0, 0, 0);
                acc[1][nt] = __builtin_amdgcn_mfma_f32_32x32x16_f16(qhB, kl[nt], acc[1][nt], 0, 0, 0);
            }
            #pragma unroll
            for (int nt = 0; nt < 4; ++nt) {
                acc[0][nt] = __builtin_amdgcn_mfma_f32_32x32x16_f16(qlA, kh[nt], acc[0][nt], 0, 0, 0);
                acc[1][nt] = __builtin_amdgcn_mfma_f32_32x32x16_f16(qlB, kh[nt], acc[1][nt], 0, 0, 0);
            }
        }
        __builtin_amdgcn_sched_barrier(0);
        __builtin_amdgcn_s_barrier();   // protect buf reuse by next STAGE
        __builtin_amdgcn_sched_barrier(0);
    }
#undef STAGE

    // ---- per-wave softmax partials over its 128-col half ----
    #pragma unroll
    for (int mrep = 0; mrep < 2; ++mrep) {
        #pragma unroll
        for (int reg = 0; reg < 16; ++reg) {
            const int srow = wy * 64 + mrep * 32 + hi * 4 + (reg & 3) + 8 * (reg >> 2);
            const float qms = qmsh[srow];
            float mv[4], cvv[4];
            float mloc = -3.0e38f;
            #pragma unroll
            for (int nt = 0; nt < 4; ++nt) {
                const int tcol = wx * 128 + nt * 32 + l31;
                const float cv = acc[mrep][nt][reg];
                int dd = srow - tcol; dd = dd < 0 ? -dd : dd;
                const float valid = qms * kmsh[tcol];
                const float m = cv * __expf(nal * (float)dd) * valid - (1.0f - valid) * 1e9f;
                mv[nt] = m; cvv[nt] = cv;
                mloc = fmaxf(mloc, m);
            }
            #pragma unroll
            for (int mm = 1; mm < 32; mm <<= 1)
                mloc = fmaxf(mloc, __shfl_xor(mloc, mm, 32));
            float L = 0.0f, W = 0.0f;
            #pragma unroll
            for (int nt = 0; nt < 4; ++nt) {
                const float e = __expf(mv[nt] - mloc);
                L += e;
                W += e * cvv[nt];
            }
            #pragma unroll
            for (int mm = 1; mm < 32; mm <<= 1) {
                L += __shfl_xor(L, mm, 32);
                W += __shfl_xor(W, mm, 32);
            }
            if (l31 == 0) {
                pm[srow][wx] = mloc;
                pL[srow][wx] = L;
                pW[srow][wx] = W;
            }
        }
    }
    __syncthreads();

    // ---- merge col-halves per row, then block-reduce ----
    float contrib = 0.0f, qq = 0.0f;
    if (tid < 256) {
        const float m0 = pm[tid][0], m1 = pm[tid][1];
        const float M  = fmaxf(m0, m1);
        const float e0 = __expf(m0 - M), e1 = __expf(m1 - M);
        const float L  = pL[tid][0] * e0 + pL[tid][1] * e1;
        const float W  = pW[tid][0] * e0 + pW[tid][1] * e1;
        contrib = (W / L) * qmsh[tid];
        qq = qmsh[tid];
    }
    redA[tid] = contrib;
    redB[tid] = qq;
    __syncthreads();
    for (int off = 256; off > 0; off >>= 1) {
        if (tid < off) {
            redA[tid] += redA[tid + off];
            redB[tid] += redB[tid + off];
        }
        __syncthreads();
    }
    if (tid == 0) out[i * 32 + j] = redA[0] / fmaxf(redB[0], 1.0f);
}

// ---------------------------------------------------------------------------
extern "C" void kernel_launch(void* const* d_in, const int* in_sizes, int n_in,
                              void* d_out, int out_size, void* d_ws, size_t ws_size,
                              hipStream_t stream)
{
    const float* qe = (const float*)d_in[0];
    const float* ke = (const float*)d_in[1];
    const float* qm = (const float*)d_in[2];
    const float* km = (const float*)d_in[3];
    const float* al = (const float*)d_in[4];
    float* out = (float*)d_out;

    char* wsQ = (char*)d_ws;
    char* wsK = wsQ + WSQ_BYTES;

    hipLaunchKernelGGL(li_split_kernel, dim3((I_DIM + J_DIM) * S_DIM / 4), dim3(256),
                       0, stream, qe, ke, wsQ, wsK);
    hipLaunchKernelGGL(li_mfma_kernel, dim3(I_DIM * J_DIM), dim3(512), 0, stream,
                       wsQ, wsK, qm, km, al, out);
}